// Round 10
// baseline (208.378 us; speedup 1.0000x reference)
//
#include <hip/hip_runtime.h>
#include <math.h>

#define B_ 8
#define C_ 64
#define H_ 128
#define W_ 128
#define O_ 64
#define HW_ (H_ * W_)
#define OMS 27     // floats per om row (odd stride -> conflict-free b32); 27 channels exactly

typedef _Float16 half8v  __attribute__((ext_vector_type(8)));
typedef float    f32x4   __attribute__((ext_vector_type(4)));
typedef float    f32x16  __attribute__((ext_vector_type(16)));

// Async global->LDS, 16B per lane, dest = uniform base + lane*16 (HW rule).
__device__ __forceinline__ void load_lds16(const void* g, void* l) {
    __builtin_amdgcn_global_load_lds((const __attribute__((address_space(1))) void*)g,
                                     (__attribute__((address_space(3))) void*)l, 16, 0, 0);
}

// ws: Wch2[9*4*2*512] f16 packed per (tap,s,nhalf) lane-blocks; Womh[32*576] f16
__global__ void prep_weights(const float* __restrict__ wc,
                             const float* __restrict__ wo,
                             const float* __restrict__ wm,
                             _Float16* __restrict__ Wch2,
                             _Float16* __restrict__ Womh)
{
    int tid = blockIdx.x * blockDim.x + threadIdx.x;
    if (tid < 9 * 4096) {   // Wch2: packed so one wave-instr reads 16 consecutive lines
        int j = tid & 7, l = (tid >> 3) & 63, nh = (tid >> 9) & 1, s = (tid >> 10) & 3, tap = tid >> 12;
        int o = nh * 32 + (l & 31);
        int c = s * 16 + ((l >> 5) << 3) + j;
        Wch2[tid] = (_Float16)wc[(o * 64 + c) * 9 + tap];
    }
    if (tid < 32 * 576) {   // Womh: [n][tap*64+c] fp16, rows >=27 zero
        int n = tid / 576, tk = tid % 576;
        int tap = tk >> 6, c = tk & 63;
        float v = 0.f;
        if (n < 18)      v = wo[(n * 64 + c) * 9 + tap];
        else if (n < 27) v = wm[((n - 18) * 64 + c) * 9 + tap];
        Womh[tid] = (_Float16)v;
    }
}

// NCHW f32 -> NHWC fp16. Pixel row = 64ch * 2B = 128B = 2 cachelines.
__global__ __launch_bounds__(256) void transpose_x(const float* __restrict__ x,
                                                   _Float16* __restrict__ xT)
{
    __shared__ float tile[64][65];
    const int t = threadIdx.x;
    const int b = blockIdx.x & 7;
    const int tp = blockIdx.x >> 3;        // 0..255: 64-pixel tile within HW
    const int lane = t & 63, wv = t >> 6;
    const float* xb = x + (size_t)b * C_ * HW_;
    const int p0 = tp * 64;
#pragma unroll
    for (int j = 0; j < 16; ++j) {
        int c = wv * 16 + j;
        tile[c][lane] = xb[(size_t)c * HW_ + p0 + lane];   // 256B coalesced
    }
    __syncthreads();
    _Float16* ob = xT + ((size_t)b * HW_ + p0) * 64;
    const int px = t >> 2, c0 = (t & 3) * 16;
    half8v h0, h1;
#pragma unroll
    for (int j = 0; j < 8; ++j) h0[j] = (_Float16)tile[c0 + j][px];
#pragma unroll
    for (int j = 0; j < 8; ++j) h1[j] = (_Float16)tile[c0 + 8 + j][px];
    *(half8v*)&ob[(size_t)px * 64 + c0] = h0;
    *(half8v*)&ob[(size_t)px * 64 + c0 + 8] = h1;
}

__global__ __launch_bounds__(256, 3) void deform_mfma(
    const _Float16* __restrict__ xT,       // NHWC fp16 (phases A and B)
    const _Float16* __restrict__ Wch2,
    const _Float16* __restrict__ Womh,
    float* __restrict__ out)
{
    __shared__ char uni[32768];            // phase B corner strip
    __shared__ float omb[64 * OMS];        // raw offset/mask conv output (6912 B)
    __shared__ unsigned short pcbu[576];   // biased u8 coord pairs (x0+16)<<8|(y0+16) (1152 B)
    _Float16* strB = (_Float16*)uni;       // [corner][px][64 halfs], 256 rows * 128B

    const int t = threadIdx.x;
    const int lane = t & 63;
    const int wv = t >> 6;
    const int g = __builtin_amdgcn_readfirstlane(wv);

    const int blk = blockIdx.x;
    const int b = blk & 7;                 // XCD-batch swizzle (verified R5)
    const int rest = blk >> 3;
    const int wcol0 = (rest & 1) << 6;
    const int h = rest >> 1;
    const _Float16* xTb = xT + (size_t)b * HW_ * 64;

    // ================= phase A: offset/mask conv, direct-from-xT fp16 MFMA ======
    f32x4 cv0 = {}, cv1 = {};
    const int mrowA = (wv << 4) + (lane & 15);   // pixel within 64-col strip
    const int kqA = (lane >> 4) << 3;            // 8-half subgroup within K=32 block
    const int n0 = lane & 15;
    const int xxA = wcol0 + mrowA - 1;
    const int yyA = h - 1;

#pragma unroll
    for (int tap = 0; tap < 9; ++tap) {
        const int ty = tap / 3, tx = tap - ty * 3;
        const int yy = yyA + ty, xx = xxA + tx;
        const bool ok = (((unsigned)yy < (unsigned)H_) && ((unsigned)xx < (unsigned)W_));
        const _Float16 okh = ok ? (_Float16)1.0f : (_Float16)0.0f;
        const int yyc = min(max(yy, 0), H_ - 1), xxc = min(max(xx, 0), W_ - 1);
        const _Float16* prow = xTb + ((size_t)((yyc << 7) + xxc) << 6);
        const _Float16* wr = Womh + n0 * 576 + tap * 64;
#pragma unroll
        for (int s = 0; s < 2; ++s) {
            const int koff = (s << 5) + kqA;
            half8v a = *(const half8v*)(prow + koff);
            a = a * okh;                               // boundary zero (exact)
            half8v b0 = *(const half8v*)(wr + koff);
            half8v b1 = *(const half8v*)(wr + 16 * 576 + koff);
            cv0 = __builtin_amdgcn_mfma_f32_16x16x32_f16(a, b0, cv0, 0, 0, 0);
            cv1 = __builtin_amdgcn_mfma_f32_16x16x32_f16(a, b1, cv1, 0, 0, 0);
        }
    }

    // scatter om (verified layout; OMS=27 -> only channels 16..26 from cv1: j0<11)
    {
        const int j0 = lane & 15;
        const int pxo = (wv << 4) + ((lane >> 4) << 2);
#pragma unroll
        for (int r = 0; r < 4; ++r) {
            omb[(pxo + r) * OMS + j0] = cv0[r];
            if (j0 < 11) omb[(pxo + r) * OMS + j0 + 16] = cv1[r];
        }
    }

    // ======= bw -> registers, ONCE per block (loop-invariant in the R9 k-loop).
    // 36 x 16B = 72 VGPR; removes 144 VMEM instr + 2304 line-accesses/block from
    // the TA pipe (the R9 bottleneck). Loads overlap the transform below.
    const int mhalf = wv & 1, nhalf = wv >> 1;
    const int mrow = (mhalf << 5) + (lane & 31);
    half8v bwreg[36];
#pragma unroll
    for (int k = 0; k < 9; ++k)
#pragma unroll
        for (int s = 0; s < 4; ++s)
            bwreg[(k << 2) + s] =
                *(const half8v*)&Wch2[(((((k << 2) + s) << 1) + nhalf) << 9) + (lane << 3)];

    __syncthreads();   // scatter visible

    // ======= per-lane transform (verified R9):
    //   lane l computes pixel l's coords -> pcbu (wave 0 stores)
    //   lane computes pixel mrow's fused fp16 weights -> REGISTERS hw[9][4]
    _Float16 hw[9][4];
    {
#pragma unroll
        for (int k = 0; k < 9; ++k) {
            const int ki = k / 3, kj = k - ki * 3;     // compile-time (unrolled)
            // coords for pixel `lane`
            const float offyc = omb[lane * OMS + 2 * k];
            const float offxc = omb[lane * OMS + 2 * k + 1];
            const float pyc = (float)(h + ki - 1) + offyc;
            const float pxc = (float)(wcol0 + lane + kj - 1) + offxc;
            const int y0c = min(max((int)floorf(pyc), -16), 199) + 16;   // bias to u8
            const int x0c = min(max((int)floorf(pxc), -16), 199) + 16;
            if (wv == 0) pcbu[(k << 6) + lane] = (unsigned short)((x0c << 8) | y0c);
            // weights for pixel `mrow`
            const float offy = omb[mrow * OMS + 2 * k];
            const float offx = omb[mrow * OMS + 2 * k + 1];
            const float mr   = omb[mrow * OMS + 18 + k];
            const float mk = 1.f / (1.f + __expf(-mr));
            const float py  = (float)(h + ki - 1) + offy;
            const float pxf = (float)(wcol0 + mrow + kj - 1) + offx;
            const float y0f = floorf(py), x0f = floorf(pxf);
            const int y0 = (int)y0f, x0 = (int)x0f;
            const float wy1 = py - y0f, wx1 = pxf - x0f;
            const bool vy0 = (unsigned)y0 < (unsigned)H_;
            const bool vy1 = (unsigned)(y0 + 1) < (unsigned)H_;
            const bool vx0 = (unsigned)x0 < (unsigned)W_;
            const bool vx1 = (unsigned)(x0 + 1) < (unsigned)W_;
            const float wy0v = vy0 ? 1.f - wy1 : 0.f;
            const float wy1v = vy1 ? wy1 : 0.f;
            const float wx0v = vx0 ? (1.f - wx1) * mk : 0.f;
            const float wx1v = vx1 ? wx1 * mk : 0.f;
            hw[k][0] = (_Float16)(wy0v * wx0v);
            hw[k][1] = (_Float16)(wy0v * wx1v);
            hw[k][2] = (_Float16)(wy1v * wx0v);
            hw[k][3] = (_Float16)(wy1v * wx1v);
        }
    }
    __syncthreads();   // pcbu visible

    // ================= phase B: cooperative corner fill + packed-fp16 einsum =====
    // Fully unrolled over taps: hw[k][*] and bwreg[*] stay in registers (rule #20).
    f32x16 acc = {};
    const int kchunk = lane >> 5;          // 0/1: which 16B chunk pair
    const int fpx0 = lane >> 3;            // fill: row-within-8
    const int fslot = lane & 7;            // fill: 16B slot
    const int srcsl = (fslot ^ fpx0) << 3; // hoisted: (p&7)==fpx0 for p=(i<<3)+fpx0
    const int dy = g >> 1, dx = g & 1;     // wave g loads corner g
    const int rsw = mrow & 7;

#pragma unroll
    for (int k = 0; k < 9; ++k) {
        const int kb = k << 6;
        // ---- fill: wave g loads corner (dy,dx) rows for all 64 px, full-line coop.
#pragma unroll
        for (int i = 0; i < 8; ++i) {
            const int p = (i << 3) + fpx0;
            const unsigned pc = pcbu[kb + p];
            const int y0 = (int)(pc & 0xFFu) - 16;
            const int x0 = (int)(pc >> 8) - 16;
            const int yc = min(max(y0 + dy, 0), H_ - 1);
            const int xc = min(max(x0 + dx, 0), W_ - 1);
            const _Float16* src = xTb + ((size_t)((yc << 7) + xc) << 6) + srcsl;
            load_lds16(src, &strB[(((g << 6) + (i << 3)) << 6) + (lane << 3)]);
        }

        __builtin_amdgcn_s_waitcnt(0x0F70);   // vmcnt(0): strip loads landed
        __builtin_amdgcn_s_barrier();

#pragma unroll
        for (int s = 0; s < 4; ++s) {
            const int slot = ((s << 1) + kchunk) ^ rsw;
            const _Float16* r0 = &strB[(mrow << 6) + (slot << 3)];
            half8v v00 = *(const half8v*)(r0);            // corner (y0,x0)
            half8v v01 = *(const half8v*)(r0 + 4096);     // corner (y0,x1)
            half8v v10 = *(const half8v*)(r0 + 8192);     // corner (y1,x0)
            half8v v11 = *(const half8v*)(r0 + 12288);    // corner (y1,x1)
            half8v a = v00 * hw[k][0];                    // v_pk_mul/fma_f16 chain
            a = v01 * hw[k][1] + a;
            a = v10 * hw[k][2] + a;
            a = v11 * hw[k][3] + a;
            acc = __builtin_amdgcn_mfma_f32_32x32x16_f16(a, bwreg[(k << 2) + s], acc, 0, 0, 0);
        }
        __builtin_amdgcn_s_barrier();        // all reads done -> strip reusable
    }

    // ================= epilogue: store C (32x32 layout, verified R3) =======
    {
        const int nrow = (nhalf << 5) + (lane & 31);
        float* ob = out + ((size_t)b * O_ + nrow) * HW_ + h * W_ + wcol0;
        const int rbase = ((lane >> 5) << 2) + (mhalf << 5);
#pragma unroll
        for (int q = 0; q < 4; ++q) {
            f32x4 vv = {acc[4*q], acc[4*q+1], acc[4*q+2], acc[4*q+3]};
            *(f32x4*)&ob[rbase + 8*q] = vv;
        }
    }
}

extern "C" void kernel_launch(void* const* d_in, const int* in_sizes, int n_in,
                              void* d_out, int out_size, void* d_ws, size_t ws_size,
                              hipStream_t stream) {
    const float* x      = (const float*)d_in[0];
    const float* w_conv = (const float*)d_in[1];
    const float* w_off  = (const float*)d_in[2];
    const float* w_msk  = (const float*)d_in[3];
    float* out = (float*)d_out;

    _Float16* xT   = (_Float16*)d_ws;                       // 8*16384*64 halfs = 16.78 MB
    _Float16* Wch2 = xT + (size_t)B_ * HW_ * 64;            // 9*4096 halfs
    _Float16* Womh = Wch2 + 9 * 4096;                       // 32*576 halfs

    prep_weights<<<144, 256, 0, stream>>>(w_conv, w_off, w_msk, Wch2, Womh);
    transpose_x<<<2048, 256, 0, stream>>>(x, xT);

    deform_mfma<<<2048, 256, 0, stream>>>(xT, Wch2, Womh, out);
}

// Round 12
// 148.996 us; speedup vs baseline: 1.3985x; 1.3985x over previous
//
#include <hip/hip_runtime.h>
#include <math.h>

#define B_ 8
#define C_ 64
#define H_ 128
#define W_ 128
#define O_ 64
#define HW_ (H_ * W_)
#define OMS 27     // floats per om row (odd stride -> conflict-free b32); 27 channels exactly

typedef _Float16 half8v  __attribute__((ext_vector_type(8)));
typedef float    f32x4   __attribute__((ext_vector_type(4)));
typedef float    f32x16  __attribute__((ext_vector_type(16)));

// Async global->LDS, 16B per lane, dest = uniform base + lane*16 (HW rule).
__device__ __forceinline__ void load_lds16(const void* g, void* l) {
    __builtin_amdgcn_global_load_lds((const __attribute__((address_space(1))) void*)g,
                                     (__attribute__((address_space(3))) void*)l, 16, 0, 0);
}

// ws: Wch2[9*4*2*512] f16 packed per (tap,s,nhalf) lane-blocks; Womh[32*576] f16
__global__ void prep_weights(const float* __restrict__ wc,
                             const float* __restrict__ wo,
                             const float* __restrict__ wm,
                             _Float16* __restrict__ Wch2,
                             _Float16* __restrict__ Womh)
{
    int tid = blockIdx.x * blockDim.x + threadIdx.x;
    if (tid < 9 * 4096) {   // Wch2: packed so one wave-instr reads 16 consecutive lines
        int j = tid & 7, l = (tid >> 3) & 63, nh = (tid >> 9) & 1, s = (tid >> 10) & 3, tap = tid >> 12;
        int o = nh * 32 + (l & 31);
        int c = s * 16 + ((l >> 5) << 3) + j;
        Wch2[tid] = (_Float16)wc[(o * 64 + c) * 9 + tap];
    }
    if (tid < 32 * 576) {   // Womh: [n][tap*64+c] fp16, rows >=27 zero
        int n = tid / 576, tk = tid % 576;
        int tap = tk >> 6, c = tk & 63;
        float v = 0.f;
        if (n < 18)      v = wo[(n * 64 + c) * 9 + tap];
        else if (n < 27) v = wm[((n - 18) * 64 + c) * 9 + tap];
        Womh[tid] = (_Float16)v;
    }
}

// NCHW f32 -> NHWC fp16. Pixel row = 64ch * 2B = 128B = 2 cachelines.
__global__ __launch_bounds__(256) void transpose_x(const float* __restrict__ x,
                                                   _Float16* __restrict__ xT)
{
    __shared__ float tile[64][65];
    const int t = threadIdx.x;
    const int b = blockIdx.x & 7;
    const int tp = blockIdx.x >> 3;        // 0..255: 64-pixel tile within HW
    const int lane = t & 63, wv = t >> 6;
    const float* xb = x + (size_t)b * C_ * HW_;
    const int p0 = tp * 64;
#pragma unroll
    for (int j = 0; j < 16; ++j) {
        int c = wv * 16 + j;
        tile[c][lane] = xb[(size_t)c * HW_ + p0 + lane];   // 256B coalesced
    }
    __syncthreads();
    _Float16* ob = xT + ((size_t)b * HW_ + p0) * 64;
    const int px = t >> 2, c0 = (t & 3) * 16;
    half8v h0, h1;
#pragma unroll
    for (int j = 0; j < 8; ++j) h0[j] = (_Float16)tile[c0 + j][px];
#pragma unroll
    for (int j = 0; j < 8; ++j) h1[j] = (_Float16)tile[c0 + 8 + j][px];
    *(half8v*)&ob[(size_t)px * 64 + c0] = h0;
    *(half8v*)&ob[(size_t)px * 64 + c0 + 8] = h1;
}

__global__ __launch_bounds__(256, 3) void deform_mfma(
    const _Float16* __restrict__ xT,       // NHWC fp16 (phases A and B)
    const _Float16* __restrict__ Wch2,
    const _Float16* __restrict__ Womh,
    float* __restrict__ out)
{
    // uni layout:
    //   phase A: WomL [0, 36864)  -- XOR-granule-swizzled Womh (2304 granules, FULL copy)
    //   phase B: strB [0, 32768) + wchT [32768, 40960) (per-tap 8KB Wch2 block)
    // Aliasing is phase-disjoint: all WomL reads precede the post-scatter __syncthreads.
    __shared__ char uni[40960];
    __shared__ float omb[64 * OMS];        // raw offset/mask conv output (6912 B)
    __shared__ unsigned short pcbu[576];   // biased u8 coord pairs (x0+16)<<8|(y0+16) (1152 B)
    _Float16* strB = (_Float16*)uni;       // [corner][px][64 halfs], 256 rows * 128B
    _Float16* wchT = (_Float16*)(uni + 32768);
    const _Float16* WomL = (const _Float16*)uni;
    // total 49024 B -> 49152 block -> 3 blocks/CU

    const int t = threadIdx.x;
    const int lane = t & 63;
    const int wv = t >> 6;
    const int g = __builtin_amdgcn_readfirstlane(wv);

    const int blk = blockIdx.x;
    const int b = blk & 7;                 // XCD-batch swizzle (verified R5)
    const int rest = blk >> 3;
    const int wcol0 = (rest & 1) << 6;
    const int h = rest >> 1;
    const _Float16* xTb = xT + (size_t)b * HW_ * 64;

    // ======= stage Womh -> WomL (granule-swizzled source), FULL 2304 granules.
    // (R11 bug: Wch2 is 4608 granules -- NOT staged whole anymore; per-tap below.)
    {
        _Float16* WomW = (_Float16*)uni;
#pragma unroll
        for (int i = 0; i < 9; ++i) {
            const int G = (i << 8) + t;                    // granule id 0..2303
            const int n = (G >> 3) & 31, gp = G & 7;
            const int gl = gp ^ (n & 7);                   // pre-swizzled global src
            load_lds16(Womh + n * 576 + (i << 6) + (gl << 3), WomW + ((size_t)G << 3));
        }
    }
    __builtin_amdgcn_s_waitcnt(0x0F70);   // vmcnt(0): staging landed
    __builtin_amdgcn_s_barrier();

    // ================= phase A: offset/mask conv, xT direct + WomL from LDS ======
    f32x4 cv0 = {}, cv1 = {};
    const int mrowA = (wv << 4) + (lane & 15);   // pixel within 64-col strip
    const int kqA = (lane >> 4) << 3;            // 8-half subgroup within K=32 block
    const int qA = lane >> 4;                    // granule subindex 0..3
    const int n0 = lane & 15;
    const int xsw = n0 & 7;                      // XOR key (same for n0 and n0+16)
    const int xxA = wcol0 + mrowA - 1;
    const int yyA = h - 1;

#pragma unroll
    for (int tap = 0; tap < 9; ++tap) {
        const int ty = tap / 3, tx = tap - ty * 3;
        const int yy = yyA + ty, xx = xxA + tx;
        const bool ok = (((unsigned)yy < (unsigned)H_) && ((unsigned)xx < (unsigned)W_));
        const _Float16 okh = ok ? (_Float16)1.0f : (_Float16)0.0f;
        const int yyc = min(max(yy, 0), H_ - 1), xxc = min(max(xx, 0), W_ - 1);
        const _Float16* prow = xTb + ((size_t)((yyc << 7) + xxc) << 6);
#pragma unroll
        for (int s = 0; s < 2; ++s) {
            const int koff = (s << 5) + kqA;
            half8v a = *(const half8v*)(prow + koff);
            a = a * okh;                               // boundary zero (exact)
            const int gph = ((s << 2) + qA) ^ xsw;     // swizzled granule
            half8v b0 = *(const half8v*)&WomL[tap * 2048 + (n0 << 6) + (gph << 3)];
            half8v b1 = *(const half8v*)&WomL[tap * 2048 + ((n0 + 16) << 6) + (gph << 3)];
            cv0 = __builtin_amdgcn_mfma_f32_16x16x32_f16(a, b0, cv0, 0, 0, 0);
            cv1 = __builtin_amdgcn_mfma_f32_16x16x32_f16(a, b1, cv1, 0, 0, 0);
        }
    }

    // scatter om (verified layout; OMS=27 -> only channels 16..26 from cv1: j0<11)
    {
        const int j0 = lane & 15;
        const int pxo = (wv << 4) + ((lane >> 4) << 2);
#pragma unroll
        for (int r = 0; r < 4; ++r) {
            omb[(pxo + r) * OMS + j0] = cv0[r];
            if (j0 < 11) omb[(pxo + r) * OMS + j0 + 16] = cv1[r];
        }
    }
    __syncthreads();   // scatter visible; all WomL reads done -> strB/wchT may rewrite

    // ======= per-lane transform (verified R9):
    //   lane l computes pixel l's coords -> pcbu (wave 0 stores)
    //   lane computes pixel mrow's fused fp16 weights -> REGISTERS hw[9][4]
    const int mhalf = wv & 1, nhalf = wv >> 1;
    const int mrow = (mhalf << 5) + (lane & 31);
    _Float16 hw[9][4];
    {
#pragma unroll
        for (int k = 0; k < 9; ++k) {
            const int ki = k / 3, kj = k - ki * 3;     // compile-time (unrolled)
            // coords for pixel `lane`
            const float offyc = omb[lane * OMS + 2 * k];
            const float offxc = omb[lane * OMS + 2 * k + 1];
            const float pyc = (float)(h + ki - 1) + offyc;
            const float pxc = (float)(wcol0 + lane + kj - 1) + offxc;
            const int y0c = min(max((int)floorf(pyc), -16), 199) + 16;   // bias to u8
            const int x0c = min(max((int)floorf(pxc), -16), 199) + 16;
            if (wv == 0) pcbu[(k << 6) + lane] = (unsigned short)((x0c << 8) | y0c);
            // weights for pixel `mrow`
            const float offy = omb[mrow * OMS + 2 * k];
            const float offx = omb[mrow * OMS + 2 * k + 1];
            const float mr   = omb[mrow * OMS + 18 + k];
            const float mk = 1.f / (1.f + __expf(-mr));
            const float py  = (float)(h + ki - 1) + offy;
            const float pxf = (float)(wcol0 + mrow + kj - 1) + offx;
            const float y0f = floorf(py), x0f = floorf(pxf);
            const int y0 = (int)y0f, x0 = (int)x0f;
            const float wy1 = py - y0f, wx1 = pxf - x0f;
            const bool vy0 = (unsigned)y0 < (unsigned)H_;
            const bool vy1 = (unsigned)(y0 + 1) < (unsigned)H_;
            const bool vx0 = (unsigned)x0 < (unsigned)W_;
            const bool vx1 = (unsigned)(x0 + 1) < (unsigned)W_;
            const float wy0v = vy0 ? 1.f - wy1 : 0.f;
            const float wy1v = vy1 ? wy1 : 0.f;
            const float wx0v = vx0 ? (1.f - wx1) * mk : 0.f;
            const float wx1v = vx1 ? wx1 * mk : 0.f;
            hw[k][0] = (_Float16)(wy0v * wx0v);
            hw[k][1] = (_Float16)(wy0v * wx1v);
            hw[k][2] = (_Float16)(wy1v * wx0v);
            hw[k][3] = (_Float16)(wy1v * wx1v);
        }
    }
    __syncthreads();   // pcbu visible

    // ================= phase B: corner fill + per-tap Wch2 stage + fp16 einsum ====
    // Fully unrolled over taps: hw[k][*] stays in registers (rule #20).
    // Per tap: stage 8KB Wch2 block into wchT (2 loads/thread) alongside the fill;
    // both land under the same vmcnt(0)+barrier; trailing barrier guards rewrite.
    f32x16 acc = {};
    const int kchunk = lane >> 5;          // 0/1: which 16B chunk pair
    const int fpx0 = lane >> 3;            // fill: row-within-8
    const int fslot = lane & 7;            // fill: 16B slot
    const int srcsl = (fslot ^ fpx0) << 3; // hoisted: (p&7)==fpx0 for p=(i<<3)+fpx0
    const int dy = g >> 1, dx = g & 1;     // wave g loads corner g
    const int rsw = mrow & 7;

#pragma unroll
    for (int k = 0; k < 9; ++k) {
        const int kb = k << 6;
        // ---- stage this tap's einsum weights (contiguous 4096 halfs at Wch2+k*4096)
        load_lds16(Wch2 + (k << 12) + (t << 3),        wchT + (t << 3));
        load_lds16(Wch2 + (k << 12) + 2048 + (t << 3), wchT + 2048 + (t << 3));
        // ---- fill: wave g loads corner (dy,dx) rows for all 64 px, full-line coop.
#pragma unroll
        for (int i = 0; i < 8; ++i) {
            const int p = (i << 3) + fpx0;
            const unsigned pc = pcbu[kb + p];
            const int y0 = (int)(pc & 0xFFu) - 16;
            const int x0 = (int)(pc >> 8) - 16;
            const int yc = min(max(y0 + dy, 0), H_ - 1);
            const int xc = min(max(x0 + dx, 0), W_ - 1);
            const _Float16* src = xTb + ((size_t)((yc << 7) + xc) << 6) + srcsl;
            load_lds16(src, &strB[(((g << 6) + (i << 3)) << 6) + (lane << 3)]);
        }

        __builtin_amdgcn_s_waitcnt(0x0F70);   // vmcnt(0): strip + wchT loads landed
        __builtin_amdgcn_s_barrier();

#pragma unroll
        for (int s = 0; s < 4; ++s) {
            const int slot = ((s << 1) + kchunk) ^ rsw;
            const _Float16* r0 = &strB[(mrow << 6) + (slot << 3)];
            half8v v00 = *(const half8v*)(r0);            // corner (y0,x0)
            half8v v01 = *(const half8v*)(r0 + 4096);     // corner (y0,x1)
            half8v v10 = *(const half8v*)(r0 + 8192);     // corner (y1,x0)
            half8v v11 = *(const half8v*)(r0 + 12288);    // corner (y1,x1)
            half8v a = v00 * hw[k][0];                    // v_pk_mul/fma_f16 chain
            a = v01 * hw[k][1] + a;
            a = v10 * hw[k][2] + a;
            a = v11 * hw[k][3] + a;
            half8v bw = *(const half8v*)&wchT[(((s << 1) + nhalf) << 9) + (lane << 3)];
            acc = __builtin_amdgcn_mfma_f32_32x32x16_f16(a, bw, acc, 0, 0, 0);
        }
        __builtin_amdgcn_s_barrier();        // all reads done -> strB/wchT reusable
    }

    // ================= epilogue: store C (32x32 layout, verified R3) =======
    {
        const int nrow = (nhalf << 5) + (lane & 31);
        float* ob = out + ((size_t)b * O_ + nrow) * HW_ + h * W_ + wcol0;
        const int rbase = ((lane >> 5) << 2) + (mhalf << 5);
#pragma unroll
        for (int q = 0; q < 4; ++q) {
            f32x4 vv = {acc[4*q], acc[4*q+1], acc[4*q+2], acc[4*q+3]};
            *(f32x4*)&ob[rbase + 8*q] = vv;
        }
    }
}

extern "C" void kernel_launch(void* const* d_in, const int* in_sizes, int n_in,
                              void* d_out, int out_size, void* d_ws, size_t ws_size,
                              hipStream_t stream) {
    const float* x      = (const float*)d_in[0];
    const float* w_conv = (const float*)d_in[1];
    const float* w_off  = (const float*)d_in[2];
    const float* w_msk  = (const float*)d_in[3];
    float* out = (float*)d_out;

    _Float16* xT   = (_Float16*)d_ws;                       // 8*16384*64 halfs = 16.78 MB
    _Float16* Wch2 = xT + (size_t)B_ * HW_ * 64;            // 9*4096 halfs
    _Float16* Womh = Wch2 + 9 * 4096;                       // 32*576 halfs

    prep_weights<<<144, 256, 0, stream>>>(w_conv, w_off, w_msk, Wch2, Womh);
    transpose_x<<<2048, 256, 0, stream>>>(x, xT);

    deform_mfma<<<2048, 256, 0, stream>>>(xT, Wch2, Womh, out);
}